// Round 4
// baseline (85.344 us; speedup 1.0000x reference)
//
#include <hip/hip_runtime.h>
#include <math.h>

// Problem constants (from reference)
constexpr int Bb = 8, Cc = 16, Hh = 96, Ww = 96;
constexpr int Ho = 94, Wo = 94;          // VALID 3x3
constexpr int NC = 4;                    // n_convs
constexpr int PLANE = Ho * Wo;           // 8836

// Tiling
constexpr int TX = 32, TY = 16;          // output tile per block
constexpr int IX = TX + 2, IY = TY + 2;  // 34 x 18 input/feature tile
constexpr int NXT = 3;                   // ceil(94/32)
constexpr int NYT = 6;                   // ceil(94/16)
constexpr int FS = 12;                   // floats per pixel feature record

typedef float v2f __attribute__((ext_vector_type(2)));

__device__ __forceinline__ v2f fma2(v2f a, float b, v2f c) {
    return __builtin_elementwise_fma(a, (v2f){b, b}, c);
}

struct RowF { float4 a[3]; float4 b[3]; float c[3]; };  // 27 floats: 3 px * 9 feats

__device__ __forceinline__ void load_row(RowF& r, const float (*feat)[IX][FS],
                                         int row, int tx) {
#pragma unroll
    for (int px = 0; px < 3; ++px) {
        const float* fp = &feat[row][tx + px][0];
        r.a[px] = *(const float4*)fp;
        r.b[px] = *(const float4*)(fp + 4);
        r.c[px] = fp[8];
    }
}

// rows (lo,hi) = input rows dy, dy+1 -> output rows r0 (uses lo..), r1 (uses ..hi)
template <int DY>
__device__ __forceinline__ void process_dy(const RowF& lo, const RowF& hi,
                                           const float* __restrict__ base_w,
                                           const float* __restrict__ spline_w,
                                           const float* __restrict__ spline_scaler,
                                           v2f acc[4]) {
#pragma unroll
    for (int dx = 0; dx < 3; ++dx) {
        const int i = DY * 3 + dx;
        const v2f sl = {lo.a[dx].x, hi.a[dx].x};
        const v2f f0 = {lo.a[dx].y, hi.a[dx].y};
        const v2f f1 = {lo.a[dx].z, hi.a[dx].z};
        const v2f f2 = {lo.a[dx].w, hi.a[dx].w};
        const v2f f3 = {lo.b[dx].x, hi.b[dx].x};
        const v2f f4 = {lo.b[dx].y, hi.b[dx].y};
        const v2f f5 = {lo.b[dx].z, hi.b[dx].z};
        const v2f f6 = {lo.b[dx].w, hi.b[dx].w};
        const v2f f7 = {lo.c[dx],   hi.c[dx]};
#pragma unroll
        for (int cv = 0; cv < 4; ++cv) {
            const int wi = cv * 9 + i;
            const float bw = base_w[wi];
            const float sc = spline_scaler[wi];
            const float* sw = &spline_w[wi * 8];
            v2f dot = f0 * (v2f){sw[0], sw[0]};
            dot = fma2(f1, sw[1], dot);
            dot = fma2(f2, sw[2], dot);
            dot = fma2(f3, sw[3], dot);
            dot = fma2(f4, sw[4], dot);
            dot = fma2(f5, sw[5], dot);
            dot = fma2(f6, sw[6], dot);
            dot = fma2(f7, sw[7], dot);
            acc[cv] = fma2(sl, bw, fma2(dot, sc, acc[cv]));
        }
    }
}

__global__ __launch_bounds__(256, 4)
void kan_conv_kernel(const float* __restrict__ x,
                     const float* __restrict__ base_w,        // (4,9)
                     const float* __restrict__ spline_w,      // (4,9,8)
                     const float* __restrict__ spline_scaler, // (4,9)
                     const float* __restrict__ grid,          // (12)
                     float* __restrict__ out)                 // (8,64,94,94)
{
    __shared__ float feat[IY][IX][FS];

    const int tid = threadIdx.x;
    int blk = blockIdx.x;
    const int xt = blk % NXT; blk /= NXT;
    const int yt = blk % NYT; blk /= NYT;
    const int c  = blk % Cc;
    const int b  = blk / Cc;
    const int ox0 = xt * TX, oy0 = yt * TY;

    const float g0   = grid[0];
    const float invh = 1.0f / (grid[1] - g0);

    const float* xplane = x + (size_t)(b * Cc + c) * Hh * Ww;

    // ---------- Phase 1: per-pixel features (silu + 8 cubic B-spline bases) ----------
    for (int p = tid; p < IX * IY; p += 256) {
        const int py = p / IX, px = p % IX;
        const int gy = oy0 + py, gx = ox0 + px;
        const float v = (gy < Hh && gx < Ww) ? xplane[gy * Ww + gx] : 0.0f;

        const float sl = v / (1.0f + __expf(-v));   // silu

        // Uniform-grid cubic B-spline: interval j, local coord t in [0,1)
        const float u = (v - g0) * invh;
        int j = (int)u;                              // floor for u>=0
        if (!(u >= 0.0f && u < 11.0f)) j = -100;     // outside grid -> all bases zero
        const float t  = u - (float)j;
        const float t2 = t * t, t3 = t2 * t;
        const float omt = 1.0f - t;
        const float B0 = (1.0f / 6.0f) * omt * omt * omt;                    // idx j-3
        const float B1 = (1.0f / 6.0f) * (3.0f * t3 - 6.0f * t2 + 4.0f);     // j-2
        const float B2 = (1.0f / 6.0f) * (-3.0f * t3 + 3.0f * t2 + 3.0f * t + 1.0f); // j-1
        const float B3 = (1.0f / 6.0f) * t3;                                 // j

        float bb[8];
#pragma unroll
        for (int k = 0; k < 8; ++k) {
            float r = 0.0f;
            r = (j == k + 3) ? B0 : r;
            r = (j == k + 2) ? B1 : r;
            r = (j == k + 1) ? B2 : r;
            r = (j == k    ) ? B3 : r;
            bb[k] = r;
        }

        float4* fp = (float4*)&feat[py][px][0];
        fp[0] = make_float4(sl,    bb[0], bb[1], bb[2]);
        fp[1] = make_float4(bb[3], bb[4], bb[5], bb[6]);
        fp[2] = make_float4(bb[7], 0.0f,  0.0f,  0.0f);
    }

    __syncthreads();

    // ---------- Phase 2+3: sliding 2-row register window, packed-f32 contraction ----------
    const int tx = tid & 31;        // 0..31 -> output col ox0+tx
    const int ty = tid >> 5;        // 0..7  -> output rows 2ty, 2ty+1
    const int ox = ox0 + tx;
    const int ry = 2 * ty;          // first input row of this thread's window

    v2f acc[4] = {(v2f){0.f, 0.f}, (v2f){0.f, 0.f}, (v2f){0.f, 0.f}, (v2f){0.f, 0.f}};

    RowF ra, rb;
    load_row(ra, feat, ry + 0, tx);
    load_row(rb, feat, ry + 1, tx);
    process_dy<0>(ra, rb, base_w, spline_w, spline_scaler, acc);  // rows 0,1
    load_row(ra, feat, ry + 2, tx);
    process_dy<1>(rb, ra, base_w, spline_w, spline_scaler, acc);  // rows 1,2
    load_row(rb, feat, ry + 3, tx);
    process_dy<2>(ra, rb, base_w, spline_w, spline_scaler, acc);  // rows 2,3

    // ---------- Stores: 4 conv planes, coalesced ----------
    float* obase = out + (size_t)((b * Cc + c) * NC) * PLANE;
#pragma unroll
    for (int r = 0; r < 2; ++r) {
        const int oy = oy0 + ry + r;
        if (ox < Wo && oy < Ho) {
            float* op = obase + oy * Wo + ox;
            op[0 * PLANE] = (r == 0) ? acc[0].x : acc[0].y;
            op[1 * PLANE] = (r == 0) ? acc[1].x : acc[1].y;
            op[2 * PLANE] = (r == 0) ? acc[2].x : acc[2].y;
            op[3 * PLANE] = (r == 0) ? acc[3].x : acc[3].y;
        }
    }
}

extern "C" void kernel_launch(void* const* d_in, const int* in_sizes, int n_in,
                              void* d_out, int out_size, void* d_ws, size_t ws_size,
                              hipStream_t stream) {
    const float* x             = (const float*)d_in[0];
    const float* base_w        = (const float*)d_in[1];
    const float* spline_w      = (const float*)d_in[2];
    const float* spline_scaler = (const float*)d_in[3];
    const float* grid          = (const float*)d_in[4];
    float* out = (float*)d_out;

    const int nblocks = Bb * Cc * NYT * NXT;  // 8*16*6*3 = 2304
    kan_conv_kernel<<<nblocks, 256, 0, stream>>>(x, base_w, spline_w,
                                                 spline_scaler, grid, out);
}

// Round 5
// 25.089 us; speedup vs baseline: 3.4017x; 3.4017x over previous
//
#include <hip/hip_runtime.h>
#include <math.h>

// Problem constants (from reference)
constexpr int Bb = 8, Cc = 16, Hh = 96, Ww = 96;
constexpr int Ho = 94, Wo = 94;          // VALID 3x3
constexpr int NC = 4;                    // n_convs
constexpr int PLANE = Ho * Wo;           // 8836

// Tiling: small tiles -> 4608 blocks -> ~8 blocks/CU -> 8 waves/SIMD occupancy
constexpr int TX = 16, TY = 16;          // output tile per block (1 output/thread)
constexpr int IX = TX + 2, IY = TY + 2;  // 18 x 18 input/feature tile
constexpr int NXT = 6, NYT = 6;          // ceil(94/16)
constexpr int FS = 12;                   // floats per pixel record: b0..b7, silu, pad3

typedef float v2f __attribute__((ext_vector_type(2)));

__global__ __launch_bounds__(256)
void kan_conv_kernel(const float* __restrict__ x,
                     const float* __restrict__ base_w,        // (4,9)
                     const float* __restrict__ spline_w,      // (4,9,8)
                     const float* __restrict__ spline_scaler, // (4,9)
                     const float* __restrict__ grid,          // (12)
                     float* __restrict__ out)                 // (8,64,94,94)
{
    __shared__ float feat[IY][IX][FS];   // 18*18*12*4 = 15552 B

    const int tid = threadIdx.x;
    int blk = blockIdx.x;
    const int xt = blk % NXT; blk /= NXT;
    const int yt = blk % NYT; blk /= NYT;
    const int c  = blk % Cc;
    const int b  = blk / Cc;
    const int ox0 = xt * TX, oy0 = yt * TY;

    const float g0   = grid[0];
    const float invh = 1.0f / (grid[1] - g0);

    const float* xplane = x + (size_t)(b * Cc + c) * Hh * Ww;

    // ---------- Phase 1: per-pixel features (8 cubic B-spline bases + silu) ----------
    for (int p = tid; p < IX * IY; p += 256) {
        const int py = p / IX, px = p % IX;
        const int gy = oy0 + py, gx = ox0 + px;
        const float v = (gy < Hh && gx < Ww) ? xplane[gy * Ww + gx] : 0.0f;

        const float sl = v / (1.0f + __expf(-v));   // silu

        // Uniform-grid cubic B-spline: interval j, local coord t in [0,1)
        const float u = (v - g0) * invh;
        int j = (int)u;                              // floor for u>=0
        if (!(u >= 0.0f && u < 11.0f)) j = -100;     // outside grid -> all bases zero
        const float t  = u - (float)j;
        const float t2 = t * t, t3 = t2 * t;
        const float omt = 1.0f - t;
        const float B0 = (1.0f / 6.0f) * omt * omt * omt;                    // idx j-3
        const float B1 = (1.0f / 6.0f) * (3.0f * t3 - 6.0f * t2 + 4.0f);     // j-2
        const float B2 = (1.0f / 6.0f) * (-3.0f * t3 + 3.0f * t2 + 3.0f * t + 1.0f); // j-1
        const float B3 = (1.0f / 6.0f) * t3;                                 // j

        float bb[8];
#pragma unroll
        for (int k = 0; k < 8; ++k) {
            float r = 0.0f;
            r = (j == k + 3) ? B0 : r;
            r = (j == k + 2) ? B1 : r;
            r = (j == k + 1) ? B2 : r;
            r = (j == k    ) ? B3 : r;
            bb[k] = r;
        }

        float* fp = &feat[py][px][0];
        *(float4*)(fp + 0) = make_float4(bb[0], bb[1], bb[2], bb[3]);
        *(float4*)(fp + 4) = make_float4(bb[4], bb[5], bb[6], bb[7]);
        fp[8] = sl;
    }

    __syncthreads();

    // ---------- Phase 2: 1 output/thread, pk-paired 8-dot per (conv, position) ----------
    const int tx = tid & 15;
    const int ty = tid >> 4;
    const int ox = ox0 + tx;
    const int oy = oy0 + ty;

    float acc0 = 0.f, acc1 = 0.f, acc2 = 0.f, acc3 = 0.f;

#pragma unroll
    for (int dy = 0; dy < 3; ++dy) {
#pragma unroll
        for (int dx = 0; dx < 3; ++dx) {
            const int i = dy * 3 + dx;
            const float* fp = &feat[ty + dy][tx + dx][0];
            const float4 fA = *(const float4*)(fp + 0);   // b0..b3
            const float4 fB = *(const float4*)(fp + 4);   // b4..b7
            const float  sl = fp[8];
            const v2f p01 = {fA.x, fA.y};
            const v2f p23 = {fA.z, fA.w};
            const v2f p45 = {fB.x, fB.y};
            const v2f p67 = {fB.z, fB.w};

#pragma unroll
            for (int cv = 0; cv < 4; ++cv) {
                const int wi = cv * 9 + i;
                const v2f* swp = (const v2f*)(spline_w + wi * 8);  // uniform -> s_load
                v2f d = p01 * swp[0];
                d = __builtin_elementwise_fma(p23, swp[1], d);
                d = __builtin_elementwise_fma(p45, swp[2], d);
                d = __builtin_elementwise_fma(p67, swp[3], d);
                const float ds = d.x + d.y;
                const float a = fmaf(sl, base_w[wi], spline_scaler[wi] * ds);
                if      (cv == 0) acc0 += a;
                else if (cv == 1) acc1 += a;
                else if (cv == 2) acc2 += a;
                else              acc3 += a;
            }
        }
    }

    // ---------- Stores: 4 conv planes, coalesced ----------
    if (ox < Wo && oy < Ho) {
        float* op = out + (size_t)((b * Cc + c) * NC) * PLANE + oy * Wo + ox;
        op[0 * PLANE] = acc0;
        op[1 * PLANE] = acc1;
        op[2 * PLANE] = acc2;
        op[3 * PLANE] = acc3;
    }
}

extern "C" void kernel_launch(void* const* d_in, const int* in_sizes, int n_in,
                              void* d_out, int out_size, void* d_ws, size_t ws_size,
                              hipStream_t stream) {
    const float* x             = (const float*)d_in[0];
    const float* base_w        = (const float*)d_in[1];
    const float* spline_w      = (const float*)d_in[2];
    const float* spline_scaler = (const float*)d_in[3];
    const float* grid          = (const float*)d_in[4];
    float* out = (float*)d_out;

    const int nblocks = Bb * Cc * NYT * NXT;  // 8*16*6*6 = 4608
    kan_conv_kernel<<<nblocks, 256, 0, stream>>>(x, base_w, spline_w,
                                                 spline_scaler, grid, out);
}